// Round 1
// baseline (175.134 us; speedup 1.0000x reference)
//
#include <hip/hip_runtime.h>
#include <stdint.h>

// ENAS LSTM controller. R12: decentralized sampling + true register residency.
//  - R11 evidence: VGPR_Count=128 while wihr/whhr alone need 128 + w1c/w2c +
//    live state -> compiler remat/spilled the weights; each cell re-streamed
//    ~256KB/wg from L2/scratch (FETCH 8.5MB >> 2.9MB inputs). Fix:
//    __launch_bounds__(512,1) -> 256-VGPR budget (the max an 8-wave wg can
//    schedule at 2 waves/SIMD anyway; we run 48 wgs on 256 CUs so occupancy
//    is irrelevant in this latency-chain regime).
//  - R11 critical path: per sampled cell, h/y exchange RT THEN a second
//    index-broadcast RT (wg0 samples, peers poll). The y mailbox is global:
//    every wg now reads all 8 y partials, reduces in identical FP order, and
//    runs the threefry sampling redundantly -> bitwise-identical selL in all
//    wgs, ZERO index RTs (10 removed from the chain).
//  - y mailbox switched to self-validating words ((YTAG|k)<<32 | f32bits),
//    one per element, like the proven h words: no pack barrier, no tag-order
//    barrier, no tag poll phase. Poll phase split: tid<256 publishes y then
//    polls h; tid>=256 polls the 8 y words (grouped 8-load retry) + reduces.
//  - All FP associations preserved bitwise vs R11 (gate 4-slice sum gathered
//    in ascending slice order via shfl; y = (sum16+sum16), then ascending-p
//    sum seeded 0.0f) so no sampled index can flip.
//  - 2-slot rotation safety unchanged: wg publishes k+2 only after polling
//    all of k+1's h/y, which peers publish only after their barrier-ordered
//    consumption of slot k.
//  - ws need 221,312 B (proven >= 221,696 since ctrl_v10 ran); R8-style
//    fallback kept for safety.

#define NBLK  6
#define PWG   8
#define THR   512
#define TINYF 1.17549435e-38f
#define HTAGB 0xC3B00000u
#define YTAGB 0xE1700000u
#define DONE_MAGIC 0x444f4e45

typedef unsigned long long u64;
struct U2 { uint32_t x, y; };

// ---- v12 ws layout (bytes) ----
#define W_DONE 0u        // int[8]
#define W_PART 64u       // float[12]
#define W_HX   128u      // u64[2][6][256] = 24576
#define W_YMB  24704u    // u64[2][6][8][256] = 196608
#define W_NEED 221312u

// ---- fallback (R8/R10 small) ws layout ----
#define S_READY 0u
#define S_DONE  192u
#define S_PART  224u
#define S_HP    320u
#define S_ACC   24896u
#define FXS     67108864.0f
#define READY_MAGIC 0x52454459

// Threefry-2x32, 20 rounds (Random123 / JAX). Key (k0,k1), counter (c0,c1).
__device__ __forceinline__ U2 tf2x32(uint32_t k0, uint32_t k1,
                                     uint32_t c0, uint32_t c1) {
  uint32_t ks2 = k0 ^ k1 ^ 0x1BD11BDAu;
  uint32_t x0 = c0 + k0, x1 = c1 + k1;
#define TFR(r) { x0 += x1; x1 = (x1 << (r)) | (x1 >> (32 - (r))); x1 ^= x0; }
  TFR(13) TFR(15) TFR(26) TFR(6)   x0 += k1;  x1 += ks2 + 1u;
  TFR(17) TFR(29) TFR(16) TFR(24)  x0 += ks2; x1 += k0 + 2u;
  TFR(13) TFR(15) TFR(26) TFR(6)   x0 += k0;  x1 += k1 + 3u;
  TFR(17) TFR(29) TFR(16) TFR(24)  x0 += k1;  x1 += ks2 + 4u;
  TFR(13) TFR(15) TFR(26) TFR(6)   x0 += ks2; x1 += k0 + 5u;
#undef TFR
  U2 r; r.x = x0; r.y = x1; return r;
}

__device__ __forceinline__ float sigf(float x) {
  return 1.0f / (1.0f + expf(-x));
}
// relaxed agent-scope (LLC-resolved) accessors -- the only sync primitives.
__device__ __forceinline__ void istore(int* p, int v) {
  __hip_atomic_store(p, v, __ATOMIC_RELAXED, __HIP_MEMORY_SCOPE_AGENT);
}
__device__ __forceinline__ int iload(const int* p) {
  return __hip_atomic_load(p, __ATOMIC_RELAXED, __HIP_MEMORY_SCOPE_AGENT);
}
__device__ __forceinline__ void hstore(u64* p, u64 v) {
  __hip_atomic_store(p, v, __ATOMIC_RELAXED, __HIP_MEMORY_SCOPE_AGENT);
}
__device__ __forceinline__ u64 hload(const u64* p) {
  return __hip_atomic_load(p, __ATOMIC_RELAXED, __HIP_MEMORY_SCOPE_AGENT);
}
__device__ __forceinline__ void fstore(float* p, float v) {
  __hip_atomic_store(p, v, __ATOMIC_RELAXED, __HIP_MEMORY_SCOPE_AGENT);
}
__device__ __forceinline__ float fload(const float* p) {
  return __hip_atomic_load(p, __ATOMIC_RELAXED, __HIP_MEMORY_SCOPE_AGENT);
}
__device__ __forceinline__ u64 pollw(const u64* p, uint32_t want) {
  u64 v;
  for (;;) {
    v = hload(p);
    if ((uint32_t)(v >> 32) == want) return v;
    __builtin_amdgcn_s_sleep(1);
  }
}

// =================== R12 kernel ============================================
__global__ __launch_bounds__(THR, 1) void ctrl_v12(
    const float* __restrict__ enc_w,
    const float* __restrict__ wih,
    const float* __restrict__ whh,
    const float* __restrict__ b_ih,
    const float* __restrict__ b_hh,
    const float* __restrict__ w1,
    const float* __restrict__ w2,
    const float* __restrict__ vvec,
    unsigned char* __restrict__ ws,
    float* __restrict__ out) {

  const int b = blockIdx.x & 7;      // XCD swizzle: chain b -> XCD b (if RR)
  const int p = blockIdx.x >> 3;
  if (b >= NBLK) return;
  const int tid = threadIdx.x;

  int*   done = (int*)(ws + W_DONE);
  float* part = (float*)(ws + W_PART);
  u64*   hx   = (u64*)(ws + W_HX);    // [2][6][256] tagged h words
  u64*   ymb  = (u64*)(ws + W_YMB);   // [2][6][8][256] tagged y words

  // gate GEMV: row-adjacent k-slices (4 lanes/row) -> in-wave shfl reduce
  const int r4 = tid >> 2, s4 = tid & 3;
  const int grow = (r4 >> 5) * 256 + p * 32 + (r4 & 31);
  const int k0 = s4 * 64;
  // y-partial: element rr, col half ks (cols p*32 + ks*16 + j) -- as R11
  const int rr = tid & 255, ks = tid >> 8;
  const int cb = p * 32 + ks * 16;

  __shared__ __align__(16) float gateL[THR];
  __shared__ __align__(16) float hL[256], encL[256], vL[256];
  __shared__ __align__(16) float anchL[4][256];
  __shared__ __align__(16) float w2hS[256], aw1S[6][256];
  __shared__ float rowSumL[128], biasS[128], h2S[32];
  __shared__ float logitL[8];
  __shared__ int   selL;

  if (tid < 256) { encL[tid] = enc_w[tid]; vL[tid] = vvec[tid]; }
  if (tid < 128) {
    int r = (tid >> 5) * 256 + p * 32 + (tid & 31);
    biasS[tid] = b_ih[r] + b_hh[r];
  }

  // register-resident weights: 128 VGPRs wih+whh, 32 VGPRs w1c/w2c.
  // __launch_bounds__(512,1) -> 256-VGPR budget so these actually stay.
  float4 wihr[16], whhr[16];
  #pragma unroll
  for (int c = 0; c < 16; ++c) {
    wihr[c] = *(const float4*)(wih + grow * 256 + k0 + c * 4);
    whhr[c] = *(const float4*)(whh + grow * 256 + k0 + c * 4);
  }
  float w1c[16], w2c[16];
  #pragma unroll
  for (int j = 0; j < 16; ++j) {
    w1c[j] = w1[rr * 256 + cb + j];
    w2c[j] = w2[rr * 256 + cb + j];
  }
  __syncthreads();

  auto dotIH = [&](const float* x) {
    float a = 0.0f;
    #pragma unroll
    for (int c = 0; c < 16; ++c) {
      float4 xv = *(const float4*)(x + k0 + c * 4);
      float4 w = wihr[c];
      a += w.x * xv.x + w.y * xv.y + w.z * xv.z + w.w * xv.w;
    }
    return a;
  };
  auto dotHH = [&]() {
    float a = 0.0f;
    #pragma unroll
    for (int c = 0; c < 16; ++c) {
      float4 xv = *(const float4*)(hL + k0 + c * 4);
      float4 w = whhr[c];
      a += w.x * xv.x + w.y * xv.y + w.z * xv.z + w.w * xv.w;
    }
    return a;
  };

  const float encih = dotIH(encL);   // wih @ enc, reused by all enc cells

  float cv = 0.0f;                            // c for element p*32+tid (tid<32)
  U2 bk = tf2x32(0u, 42u, 0u, (uint32_t)b);   // fold_in(key(42), b)
  int k = 1, step = 0;
  float lpAcc = 0.0f, entAcc = 0.0f;

  // One cell + exchange. mode 0: y = w2@h -> w2hS (all wgs);
  // mode 1: y = w1@h -> aw1S[aid] (+ anchor h -> anchL[cid], all wgs);
  // mode 2: last cell (no exchange).
  auto cell = [&](float gacc, int mode, int aid, int cid) {
    // 4-slice gate row sum, gathered ascending (bitwise == R11's serial sum)
    float a1 = __shfl_xor(gacc, 1);
    float a2 = __shfl_xor(gacc, 2);
    float a3 = __shfl_xor(gacc, 3);
    if (s4 == 0) rowSumL[r4] = ((gacc + a1) + a2) + a3 + biasS[r4];
    __syncthreads();
    if (tid < 32) {
      float gi = rowSumL[tid],       gf = rowSumL[32 + tid];
      float gg2 = rowSumL[64 + tid], go = rowSumL[96 + tid];
      float c2 = sigf(gf) * cv + sigf(gi) * tanhf(gg2);
      float h2 = sigf(go) * tanhf(c2);
      cv = c2;
      h2S[tid] = h2;
      if (mode == 2) {
        if (b == NBLK - 1) { out[62 + p * 32 + tid] = cv; out[318 + p * 32 + tid] = h2; }
      } else {                               // publish own h ASAP (tagged)
        hstore(&hx[(k & 1) * 1536 + b * 256 + p * 32 + tid],
               ((u64)(HTAGB | (uint32_t)k) << 32) | (u64)__float_as_uint(h2));
      }
    }
    __syncthreads();                         // h2S visible
    if (mode == 2) return;

    {                                        // own y partial (16 cols each)
      const float* wc = (mode == 1) ? w1c : w2c;
      float yp = 0.0f;
      #pragma unroll
      for (int j = 0; j < 16; ++j) yp += wc[j] * h2S[ks * 16 + j];
      gateL[tid] = yp;                       // layout ks*256 + rr
    }
    __syncthreads();

    const uint32_t wantY = YTAGB | (uint32_t)k;
    const uint32_t wantH = HTAGB | (uint32_t)k;
    u64* yslot = ymb + (size_t)(k & 1) * 12288 + (size_t)b * 2048;
    if (tid < 256) {
      // publish self-validating y word: (tag|f32). (sum16+sum16) == R11 pack.
      float yp2 = gateL[tid] + gateL[256 + tid];
      hstore(yslot + p * 256 + tid,
             ((u64)wantY << 32) | (u64)__float_as_uint(yp2));
      // then poll full h
      u64 v = pollw(&hx[(k & 1) * 1536 + b * 256 + tid], wantH);
      float hv = __uint_as_float((uint32_t)v);
      hL[tid] = hv;
      if (mode == 1 && cid >= 0) anchL[cid][tid] = hv;
    } else {
      // concurrently: poll+reduce the 8 y partials (grouped retry, asc order)
      const int e = tid & 255;
      const u64* bp = yslot + e;
      u64 w[8];
      for (;;) {
        bool ok = true;
        #pragma unroll
        for (int q = 0; q < 8; ++q) {
          w[q] = hload(bp + q * 256);
          ok &= ((uint32_t)(w[q] >> 32) == wantY);
        }
        if (ok) break;
        __builtin_amdgcn_s_sleep(1);
      }
      float y = 0.0f;
      #pragma unroll
      for (int q = 0; q < 8; ++q) y += __uint_as_float((uint32_t)w[q]);
      if (mode == 1) aw1S[aid][e] = y; else w2hS[e] = y;
    }
    __syncthreads();
    ++k;
  };

  // Decentralized sampling: every wg runs identical FP ops on identical data
  // -> bitwise-identical selL; no index broadcast RT. (Math verbatim R11.)
  auto resolve = [&](int L) -> int {
    int wv = tid >> 6, lane = tid & 63;
    if (wv < L) {
      float a = 0.0f;
      #pragma unroll
      for (int j = 0; j < 4; ++j) {          // stride-64: conflict-free
        int kk = j * 64 + lane;
        a += tanhf(aw1S[wv][kk] + w2hS[kk]) * vL[kk];
      }
      a += __shfl_down(a, 32);
      a += __shfl_down(a, 16);
      a += __shfl_down(a, 8);
      a += __shfl_down(a, 4);
      a += __shfl_down(a, 2);
      a += __shfl_down(a, 1);
      if (lane == 0) logitL[wv] = a;
    }
    __syncthreads();
    if (tid < 64) {                          // wave 0: selection (R10 math)
      float lg = 0.0f, sgum = -1e30f;
      if (tid < L) {
        lg = 1.1f * tanhf(logitL[tid] * 0.2f);
        U2 sk = tf2x32(bk.x, bk.y, 0u, (uint32_t)step);
        U2 r2 = tf2x32(sk.x, sk.y, 0u, (uint32_t)tid);
        uint32_t bits = r2.x ^ r2.y;
        float u = __uint_as_float((bits >> 9) | 0x3f800000u) - 1.0f;
        u = fmaxf(TINYF, u + TINYF);         // jax uniform(tiny, 1)
        sgum = lg - logf(-logf(u));
      }
      int bi = 0;
      float best = __shfl(sgum, 0, 64);
      for (int j = 1; j < L; ++j) {
        float sj = __shfl(sgum, j, 64);
        if (sj > best) { best = sj; bi = j; }     // first-max = jnp.argmax
      }
      float mx = __shfl(lg, 0, 64);
      for (int j = 1; j < L; ++j) mx = fmaxf(mx, __shfl(lg, j, 64));
      float se = 0.0f;
      for (int j = 0; j < L; ++j) se += expf(__shfl(lg, j, 64) - mx);
      float lse = logf(se);
      float lgbi = __shfl(lg, bi, 64);
      float es = 0.0f;
      for (int j = 0; j < L; ++j) {
        float l = __shfl(lg, j, 64) - mx - lse;
        es += l * expf(l);
      }
      if (tid == 0) {
        lpAcc += -(lgbi - mx - lse);
        entAcc += -es;
        selL = bi;
        if (p == 0) out[b * 10 + step] = (float)bi;
      }
    }
    __syncthreads();
    step++;
    return selL;
  };

  // ---- chain ----
  cell(encih, 1, 0, -1);             // zero-state cell; all wgs get aw1[0]
  if (tid < 256) aw1S[1][tid] = aw1S[0][tid];
  __syncthreads();

  for (int L = 2; L <= 6; ++L) {
    { float hh = dotHH(); cell(encih + hh, 0, 0, -1); }          // cellA
    {
      float hh = dotHH();
      int s1 = resolve(L);
      float a = (s1 >= 2) ? dotIH(&anchL[s1 - 2][0]) : 0.0f;
      cell(a + hh, 0, 0, -1);                                    // cellB
    }
    {
      float hh = dotHH();
      int s2 = resolve(L);
      float a = (s2 >= 2) ? dotIH(&anchL[s2 - 2][0]) : 0.0f;
      if (L < 6) cell(a + hh, 1, L, L - 2);                      // cellC anchor
      else       cell(a + hh, 2, 0, -1);                         // last cell
    }
  }

  if (p == 0 && tid == 0) {
    fstore(&part[2 * b], lpAcc);
    fstore(&part[2 * b + 1], entAcc);
    __builtin_amdgcn_s_waitcnt(0);
    istore(&done[b], DONE_MAGIC);
    if (b == NBLK - 1) {
      float lp = 0.0f, en = 0.0f;
      for (int j = 0; j < NBLK; ++j) {
        while (iload(&done[j]) != DONE_MAGIC) __builtin_amdgcn_s_sleep(1);
        lp += fload(&part[2 * j]);
        en += fload(&part[2 * j + 1]);
      }
      out[60] = lp;
      out[61] = en;
    }
  }
}

// =================== fallback (proven R8-style; small ws) ==================
__global__ __launch_bounds__(1024) void ctrl_small(
    const float* __restrict__ enc_w,
    const float* __restrict__ wih,
    const float* __restrict__ whh,
    const float* __restrict__ b_ih,
    const float* __restrict__ b_hh,
    const float* __restrict__ w1,
    const float* __restrict__ w2,
    const float* __restrict__ vvec,
    unsigned char* __restrict__ ws,
    float* __restrict__ out) {

  const int b = blockIdx.x & 7;
  const int p = blockIdx.x >> 3;
  if (b >= NBLK) return;
  const int tid = threadIdx.x;

  int*   ready = (int*)(ws + S_READY);
  int*   done  = (int*)(ws + S_DONE);
  float* part  = (float*)(ws + S_PART);
  u64*   hp    = (u64*)(ws + S_HP);
  int*   acc   = (int*)(ws + S_ACC);

  const int rl = tid >> 3, s = tid & 7;
  const int g = rl >> 5, el = rl & 31;
  const int row = g * 256 + p * 32 + el;
  const int k0 = s * 32;
  const int rr = tid & 255, ks = tid >> 8;

  __shared__ __align__(16) float hL[256], encL[256], vL[256];
  __shared__ __align__(16) float anchL[4][256];
  __shared__ __align__(16) float partL[1024];
  __shared__ __align__(16) float w2hS[256], aw1S[6][256];
  __shared__ float rowSumL[128], biasS[128], h2S[32];
  __shared__ float logitL[8];
  __shared__ int   selL;

  if (tid < 256) { encL[tid] = enc_w[tid]; vL[tid] = vvec[tid]; }
  if (tid < 128) {
    int gg = tid >> 5, ee = tid & 31, r = gg * 256 + p * 32 + ee;
    biasS[tid] = b_ih[r] + b_hh[r];
  }

  float4 wihr[8], whhr[8];
  #pragma unroll
  for (int c = 0; c < 8; ++c) {
    int cc = (c + s) & 7;
    wihr[c] = *(const float4*)(wih + row * 256 + k0 + cc * 4);
    whhr[c] = *(const float4*)(whh + row * 256 + k0 + cc * 4);
  }
  float w1c[8], w2c[8];
  #pragma unroll
  for (int j = 0; j < 8; ++j) {
    w1c[j] = w1[rr * 256 + p * 32 + ks * 8 + j];
    w2c[j] = w2[rr * 256 + p * 32 + ks * 8 + j];
  }

  if (tid < 32) istore(&acc[1 * (NBLK * 256) + b * 256 + p * 32 + tid], 0);
  __syncthreads();
  if (tid == 0) istore(&ready[b * 8 + p], READY_MAGIC);
  if (tid < 8) {
    while (iload(&ready[b * 8 + tid]) != READY_MAGIC)
      __builtin_amdgcn_s_sleep(1);
  }
  __syncthreads();

  auto dotIH = [&](const float* x) {
    float a = 0.0f;
    #pragma unroll
    for (int c = 0; c < 8; ++c) {
      int cc = (c + s) & 7;
      float4 xv = *(const float4*)(x + k0 + cc * 4);
      float4 w = wihr[c];
      a += w.x * xv.x + w.y * xv.y + w.z * xv.z + w.w * xv.w;
    }
    return a;
  };
  auto dotHH = [&]() {
    float a = 0.0f;
    #pragma unroll
    for (int c = 0; c < 8; ++c) {
      int cc = (c + s) & 7;
      float4 xv = *(const float4*)(hL + k0 + cc * 4);
      float4 w = whhr[c];
      a += w.x * xv.x + w.y * xv.y + w.z * xv.z + w.w * xv.w;
    }
    return a;
  };

  const float encih = dotIH(encL);
  float cv = 0.0f;
  U2 bk = tf2x32(0u, 42u, 0u, (uint32_t)b);
  int k = 1, step = 0;
  float lpAcc = 0.0f, entAcc = 0.0f;

  auto cell = [&](float gacc, int mode, int aid, int cid) {
    partL[tid] = gacc;
    __syncthreads();
    if (tid < 128) {
      float ssum = 0.0f;
      #pragma unroll
      for (int j = 0; j < 8; ++j) ssum += partL[tid * 8 + j];
      rowSumL[tid] = ssum + biasS[tid];
    }
    __syncthreads();
    if (tid < 32) {
      float gi = rowSumL[tid],       gf = rowSumL[32 + tid];
      float gg2 = rowSumL[64 + tid], go = rowSumL[96 + tid];
      float c2 = sigf(gf) * cv + sigf(gi) * tanhf(gg2);
      float h2 = sigf(go) * tanhf(c2);
      cv = c2;
      h2S[tid] = h2;
      if (mode == 2 && b == NBLK - 1) {
        out[62 + p * 32 + tid] = cv;
        out[318 + p * 32 + tid] = h2;
      }
    }
    __syncthreads();
    if (mode == 2) return;
    {
      const float* wc = (mode == 1) ? w1c : w2c;
      float yp = 0.0f;
      #pragma unroll
      for (int j = 0; j < 8; ++j) yp += wc[j] * h2S[ks * 8 + j];
      atomicAdd(&acc[(k % 3) * (NBLK * 256) + b * 256 + rr],
                __float2int_rn(yp * FXS));
      if (tid < 32)
        istore(&acc[((k + 1) % 3) * (NBLK * 256) + b * 256 + p * 32 + tid], 0);
    }
    __syncthreads();
    if (tid < 32) {
      u64 pk = ((u64)(uint32_t)k << 32) | (u64)__float_as_uint(h2S[tid]);
      hstore(&hp[(k & 1) * (NBLK * 256) + b * 256 + p * 32 + tid], pk);
    }
    if (tid < 256) {
      u64 v;
      const u64* src = &hp[(k & 1) * (NBLK * 256) + b * 256 + tid];
      while ((int)(hload(src) >> 32) != k) __builtin_amdgcn_s_sleep(1);
      v = hload(src);
      float hv = __uint_as_float((uint32_t)v);
      hL[tid] = hv;
      if (mode == 1 && cid >= 0) anchL[cid][tid] = hv;
    }
    __syncthreads();
    if (tid < 256) {
      int iv = iload(&acc[(k % 3) * (NBLK * 256) + b * 256 + tid]);
      float f = (float)((double)iv * (1.0 / 67108864.0));
      if (mode == 1) aw1S[aid][tid] = f; else w2hS[tid] = f;
    }
    __syncthreads();
    ++k;
  };

  auto sample = [&](int L) -> int {
    int wv = tid >> 6, lane = tid & 63;
    if (wv < L) {
      float a = 0.0f;
      #pragma unroll
      for (int j = 0; j < 4; ++j) {
        int kk = lane * 4 + j;
        a += tanhf(aw1S[wv][kk] + w2hS[kk]) * vL[kk];
      }
      a += __shfl_down(a, 32);
      a += __shfl_down(a, 16);
      a += __shfl_down(a, 8);
      a += __shfl_down(a, 4);
      a += __shfl_down(a, 2);
      a += __shfl_down(a, 1);
      if (lane == 0) logitL[wv] = a;
    }
    __syncthreads();
    if (tid < 64) {
      float lg = 0.0f, sgum = -1e30f;
      if (tid < L) {
        lg = 1.1f * tanhf(logitL[tid] * 0.2f);
        U2 sk = tf2x32(bk.x, bk.y, 0u, (uint32_t)step);
        U2 r2 = tf2x32(sk.x, sk.y, 0u, (uint32_t)tid);
        uint32_t bits = r2.x ^ r2.y;
        float u = __uint_as_float((bits >> 9) | 0x3f800000u) - 1.0f;
        u = fmaxf(TINYF, u + TINYF);
        sgum = lg - logf(-logf(u));
      }
      int bi = 0;
      float best = __shfl(sgum, 0, 64);
      for (int j = 1; j < L; ++j) {
        float sj = __shfl(sgum, j, 64);
        if (sj > best) { best = sj; bi = j; }
      }
      float mx = __shfl(lg, 0, 64);
      for (int j = 1; j < L; ++j) mx = fmaxf(mx, __shfl(lg, j, 64));
      float se = 0.0f;
      for (int j = 0; j < L; ++j) se += expf(__shfl(lg, j, 64) - mx);
      float lse = logf(se);
      float lgbi = __shfl(lg, bi, 64);
      float es = 0.0f;
      for (int j = 0; j < L; ++j) {
        float l = __shfl(lg, j, 64) - mx - lse;
        es += l * expf(l);
      }
      if (tid == 0) {
        lpAcc += -(lgbi - mx - lse);
        entAcc += -es;
        selL = bi;
        if (p == 0) out[b * 10 + step] = (float)bi;
      }
    }
    __syncthreads();
    step++;
    return selL;
  };

  cell(encih, 1, 0, -1);
  if (tid < 256) aw1S[1][tid] = aw1S[0][tid];
  __syncthreads();
  for (int L = 2; L <= 6; ++L) {
    cell(encih + dotHH(), 0, 0, -1);
    int s1v = sample(L);
    {
      float a = (s1v >= 2) ? dotIH(&anchL[s1v - 2][0]) : 0.0f;
      cell(a + dotHH(), 0, 0, -1);
    }
    int s2v = sample(L);
    {
      float a = (s2v >= 2) ? dotIH(&anchL[s2v - 2][0]) : 0.0f;
      if (L < 6) cell(a + dotHH(), 1, L, L - 2);
      else       cell(a + dotHH(), 2, 0, -1);
    }
  }
  if (p == 0 && tid == 0) {
    fstore(&part[2 * b], lpAcc);
    fstore(&part[2 * b + 1], entAcc);
    __builtin_amdgcn_s_waitcnt(0);
    istore(&done[b], DONE_MAGIC);
    if (b == NBLK - 1) {
      float lp = 0.0f, en = 0.0f;
      for (int j = 0; j < NBLK; ++j) {
        while (iload(&done[j]) != DONE_MAGIC) __builtin_amdgcn_s_sleep(1);
        lp += fload(&part[2 * j]);
        en += fload(&part[2 * j + 1]);
      }
      out[60] = lp;
      out[61] = en;
    }
  }
}

extern "C" void kernel_launch(void* const* d_in, const int* in_sizes, int n_in,
                              void* d_out, int out_size, void* d_ws, size_t ws_size,
                              hipStream_t stream) {
  const float* enc = (const float*)d_in[0];
  const float* wih = (const float*)d_in[1];
  const float* whh = (const float*)d_in[2];
  const float* bih = (const float*)d_in[3];
  const float* bhh = (const float*)d_in[4];
  const float* w1  = (const float*)d_in[5];
  const float* w2  = (const float*)d_in[6];
  const float* v   = (const float*)d_in[7];
  unsigned char* ws = (unsigned char*)d_ws;
  float* out = (float*)d_out;

  if (ws_size >= W_NEED) {
    ctrl_v12<<<dim3(64), dim3(THR), 0, stream>>>(
        enc, wih, whh, bih, bhh, w1, w2, v, ws, out);
  } else {
    ctrl_small<<<dim3(64), dim3(1024), 0, stream>>>(
        enc, wih, whh, bih, bhh, w1, w2, v, ws, out);
  }
}

// Round 2
// 161.450 us; speedup vs baseline: 1.0848x; 1.0848x over previous
//
#include <hip/hip_runtime.h>
#include <stdint.h>

// ENAS LSTM controller. R13: R11 structure + decentralized sampling done right.
//  - R12 post-mortem: (a) 4-lane k-slice gate mapping created 4-way LDS bank
//    conflicts (1.49M cy) inside dotIH/dotHH on the critical path -> REVERTED
//    to R11's wave-uniform slices (s = tid>>7, broadcast reads, 0 conflicts).
//    (b) grouped 8-load y-poll re-read 16KB/wg/iter from 48 pollers -> LLC
//    poll storm. Fixed: per-element tagged words, reader seeds OWN partial
//    from LDS (polls only 7 remote), and re-reads ONLY not-yet-valid words
//    (steady-state traffic == h-poll, which R11 sustained at 87us).
//    (c) VGPR theory dead: 8-wave wgs pin 2 waves/SIMD; compiler parks
//    weights in AGPRs (unified file) regardless. launch_bounds back to (512,2).
//  - Kept from R12 (the good part): every wg reduces y and samples redundantly
//    (bitwise-identical threefry + FP order) -> ZERO index-broadcast RTs
//    (10 removed vs R11). h-poll (waves 0-3) overlaps y-poll (waves 4-7).
//  - All FP associations bitwise == R11: gate sum ascending j via LDS reduce,
//    y = (sum16+sum16) then ascending-p sum seeded 0.0f, R10 sampling math.
//  - 2-slot rotation safety: a wg publishes slot k+2 only after consuming all
//    of k+1, which peers publish only after consuming k (unchanged argument).
//  - ws need 221,312 B (proven >= 221,696 since ctrl_v10); R8 fallback kept.

#define NBLK  6
#define PWG   8
#define THR   512
#define TINYF 1.17549435e-38f
#define HTAGB 0xC3B00000u
#define YTAGB 0xE1700000u
#define DONE_MAGIC 0x444f4e45

typedef unsigned long long u64;
struct U2 { uint32_t x, y; };

// ---- v13 ws layout (bytes) ----
#define W_DONE 0u        // int[8]
#define W_PART 64u       // float[12]
#define W_HX   128u      // u64[2][6][256] = 24576
#define W_YMB  24704u    // u64[2][6][8][256] = 196608
#define W_NEED 221312u

// ---- fallback (R8/R10 small) ws layout ----
#define S_READY 0u
#define S_DONE  192u
#define S_PART  224u
#define S_HP    320u
#define S_ACC   24896u
#define FXS     67108864.0f
#define READY_MAGIC 0x52454459

// Threefry-2x32, 20 rounds (Random123 / JAX). Key (k0,k1), counter (c0,c1).
__device__ __forceinline__ U2 tf2x32(uint32_t k0, uint32_t k1,
                                     uint32_t c0, uint32_t c1) {
  uint32_t ks2 = k0 ^ k1 ^ 0x1BD11BDAu;
  uint32_t x0 = c0 + k0, x1 = c1 + k1;
#define TFR(r) { x0 += x1; x1 = (x1 << (r)) | (x1 >> (32 - (r))); x1 ^= x0; }
  TFR(13) TFR(15) TFR(26) TFR(6)   x0 += k1;  x1 += ks2 + 1u;
  TFR(17) TFR(29) TFR(16) TFR(24)  x0 += ks2; x1 += k0 + 2u;
  TFR(13) TFR(15) TFR(26) TFR(6)   x0 += k0;  x1 += k1 + 3u;
  TFR(17) TFR(29) TFR(16) TFR(24)  x0 += k1;  x1 += ks2 + 4u;
  TFR(13) TFR(15) TFR(26) TFR(6)   x0 += ks2; x1 += k0 + 5u;
#undef TFR
  U2 r; r.x = x0; r.y = x1; return r;
}

__device__ __forceinline__ float sigf(float x) {
  return 1.0f / (1.0f + expf(-x));
}
// relaxed agent-scope (LLC-resolved) accessors -- the only sync primitives.
__device__ __forceinline__ void istore(int* p, int v) {
  __hip_atomic_store(p, v, __ATOMIC_RELAXED, __HIP_MEMORY_SCOPE_AGENT);
}
__device__ __forceinline__ int iload(const int* p) {
  return __hip_atomic_load(p, __ATOMIC_RELAXED, __HIP_MEMORY_SCOPE_AGENT);
}
__device__ __forceinline__ void hstore(u64* p, u64 v) {
  __hip_atomic_store(p, v, __ATOMIC_RELAXED, __HIP_MEMORY_SCOPE_AGENT);
}
__device__ __forceinline__ u64 hload(const u64* p) {
  return __hip_atomic_load(p, __ATOMIC_RELAXED, __HIP_MEMORY_SCOPE_AGENT);
}
__device__ __forceinline__ void fstore(float* p, float v) {
  __hip_atomic_store(p, v, __ATOMIC_RELAXED, __HIP_MEMORY_SCOPE_AGENT);
}
__device__ __forceinline__ float fload(const float* p) {
  return __hip_atomic_load(p, __ATOMIC_RELAXED, __HIP_MEMORY_SCOPE_AGENT);
}
__device__ __forceinline__ u64 pollw(const u64* p, uint32_t want) {
  u64 v;
  for (;;) {
    v = hload(p);
    if ((uint32_t)(v >> 32) == want) return v;
    __builtin_amdgcn_s_sleep(1);
  }
}

// =================== R13 kernel ============================================
__global__ __launch_bounds__(THR, 2) void ctrl_v13(
    const float* __restrict__ enc_w,
    const float* __restrict__ wih,
    const float* __restrict__ whh,
    const float* __restrict__ b_ih,
    const float* __restrict__ b_hh,
    const float* __restrict__ w1,
    const float* __restrict__ w2,
    const float* __restrict__ vvec,
    unsigned char* __restrict__ ws,
    float* __restrict__ out) {

  const int b = blockIdx.x & 7;      // XCD swizzle: chain b -> XCD b (if RR)
  const int p = blockIdx.x >> 3;
  if (b >= NBLK) return;
  const int tid = threadIdx.x;

  int*   done = (int*)(ws + W_DONE);
  float* part = (float*)(ws + W_PART);
  u64*   hx   = (u64*)(ws + W_HX);    // [2][6][256] tagged h words
  u64*   ymb  = (u64*)(ws + W_YMB);   // [2][6][8][256] tagged y words

  // gate GEMV: 128 local rows x 4 k-slices of 64; s wave-uniform -> all LDS
  // x-vector reads are broadcasts (0 bank conflicts, proven R11).
  const int rl = tid & 127, s = tid >> 7;
  const int grow = (rl >> 5) * 256 + p * 32 + (rl & 31);
  const int k0 = s * 64;
  // y-partial: element rr, col half ks (cols p*32 + ks*16 + j)
  const int rr = tid & 255, ks = tid >> 8;
  const int cb = p * 32 + ks * 16;

  __shared__ __align__(16) float gateL[THR];
  __shared__ __align__(16) float hL[256], encL[256], vL[256];
  __shared__ __align__(16) float anchL[4][256];
  __shared__ __align__(16) float w2hS[256], aw1S[6][256];
  __shared__ float rowSumL[128], biasS[128], h2S[32];
  __shared__ float logitL[8];
  __shared__ int   selL;

  if (tid < 256) { encL[tid] = enc_w[tid]; vL[tid] = vvec[tid]; }
  if (tid < 128) {
    int r = (tid >> 5) * 256 + p * 32 + (tid & 31);
    biasS[tid] = b_ih[r] + b_hh[r];
  }

  // weights: compiler keeps these in the unified VGPR/AGPR file (R11-proven)
  float4 wihr[16], whhr[16];
  #pragma unroll
  for (int c = 0; c < 16; ++c) {
    wihr[c] = *(const float4*)(wih + grow * 256 + k0 + c * 4);
    whhr[c] = *(const float4*)(whh + grow * 256 + k0 + c * 4);
  }
  float w1c[16], w2c[16];
  #pragma unroll
  for (int j = 0; j < 16; ++j) {
    w1c[j] = w1[rr * 256 + cb + j];
    w2c[j] = w2[rr * 256 + cb + j];
  }
  __syncthreads();

  auto dotIH = [&](const float* x) {
    float a = 0.0f;
    #pragma unroll
    for (int c = 0; c < 16; ++c) {
      float4 xv = *(const float4*)(x + k0 + c * 4);
      float4 w = wihr[c];
      a += w.x * xv.x + w.y * xv.y + w.z * xv.z + w.w * xv.w;
    }
    return a;
  };
  auto dotHH = [&]() {
    float a = 0.0f;
    #pragma unroll
    for (int c = 0; c < 16; ++c) {
      float4 xv = *(const float4*)(hL + k0 + c * 4);
      float4 w = whhr[c];
      a += w.x * xv.x + w.y * xv.y + w.z * xv.z + w.w * xv.w;
    }
    return a;
  };

  const float encih = dotIH(encL);   // wih @ enc, reused by all enc cells

  float cv = 0.0f;                            // c for element p*32+tid (tid<32)
  U2 bk = tf2x32(0u, 42u, 0u, (uint32_t)b);   // fold_in(key(42), b)
  int k = 1, step = 0;
  float lpAcc = 0.0f, entAcc = 0.0f;

  // One cell + exchange. mode 0: y = w2@h -> w2hS (all wgs);
  // mode 1: y = w1@h -> aw1S[aid] (+ anchor h -> anchL[cid], all wgs);
  // mode 2: last cell (no exchange).
  auto cell = [&](float gacc, int mode, int aid, int cid) {
    gateL[tid] = gacc;                       // tid = s*128 + rl
    __syncthreads();
    if (tid < 128) {
      float ssum = 0.0f;
      #pragma unroll
      for (int j = 0; j < 4; ++j) ssum += gateL[j * 128 + tid];
      rowSumL[tid] = ssum + biasS[tid];
    }
    __syncthreads();
    if (tid < 32) {
      float gi = rowSumL[tid],       gf = rowSumL[32 + tid];
      float gg2 = rowSumL[64 + tid], go = rowSumL[96 + tid];
      float c2 = sigf(gf) * cv + sigf(gi) * tanhf(gg2);
      float h2 = sigf(go) * tanhf(c2);
      cv = c2;
      h2S[tid] = h2;
      if (mode == 2) {
        if (b == NBLK - 1) { out[62 + p * 32 + tid] = cv; out[318 + p * 32 + tid] = h2; }
      } else {                               // publish own h ASAP (tagged)
        hstore(&hx[(k & 1) * 1536 + b * 256 + p * 32 + tid],
               ((u64)(HTAGB | (uint32_t)k) << 32) | (u64)__float_as_uint(h2));
      }
    }
    __syncthreads();                         // h2S visible
    if (mode == 2) return;

    {                                        // own y partial (16 cols each)
      const float* wc = (mode == 1) ? w1c : w2c;
      float yp = 0.0f;
      #pragma unroll
      for (int j = 0; j < 16; ++j) yp += wc[j] * h2S[ks * 16 + j];
      gateL[tid] = yp;                       // layout ks*256 + rr
    }
    __syncthreads();

    const uint32_t wantY = YTAGB | (uint32_t)k;
    const uint32_t wantH = HTAGB | (uint32_t)k;
    u64* yslot = ymb + (size_t)(k & 1) * 12288 + (size_t)b * 2048;
    if (tid < 256) {
      // publish self-validating y word: (tag|f32). (sum16+sum16) == R11 pack.
      float yp2 = gateL[tid] + gateL[256 + tid];
      hstore(yslot + p * 256 + tid,
             ((u64)wantY << 32) | (u64)__float_as_uint(yp2));
      // then poll full h (each lane stops once its word is valid)
      u64 v = pollw(&hx[(k & 1) * 1536 + b * 256 + tid], wantH);
      float hv = __uint_as_float((uint32_t)v);
      hL[tid] = hv;
      if (mode == 1 && cid >= 0) anchL[cid][tid] = hv;
    } else {
      // waves 4-7 concurrently gather the 8 y partials for element e.
      // Own partial comes from LDS (no self-poll); remote words re-read
      // ONLY while invalid (steady-state traffic == h-poll). Sum ascending q.
      const int e = tid - 256;
      const u64* bp = yslot + e;
      float own = gateL[e] + gateL[256 + e];
      float ys[8];
      unsigned got = 1u << p;
      #pragma unroll
      for (int q = 0; q < 8; ++q) ys[q] = (q == p) ? own : 0.0f;
      for (;;) {
        bool all = true;
        #pragma unroll
        for (int q = 0; q < 8; ++q) {
          if (!(got & (1u << q))) {
            u64 w = hload(bp + q * 256);
            if ((uint32_t)(w >> 32) == wantY) {
              ys[q] = __uint_as_float((uint32_t)w);
              got |= 1u << q;
            } else {
              all = false;
            }
          }
        }
        if (all) break;
        __builtin_amdgcn_s_sleep(1);
      }
      float y = 0.0f;
      #pragma unroll
      for (int q = 0; q < 8; ++q) y += ys[q];
      if (mode == 1) aw1S[aid][e] = y; else w2hS[e] = y;
    }
    __syncthreads();
    ++k;
  };

  // Decentralized sampling: every wg runs identical FP ops on identical data
  // -> bitwise-identical selL; no index broadcast RT. (Math verbatim R10/R11.)
  auto resolve = [&](int L) -> int {
    int wv = tid >> 6, lane = tid & 63;
    if (wv < L) {
      float a = 0.0f;
      #pragma unroll
      for (int j = 0; j < 4; ++j) {          // stride-64: conflict-free
        int kk = j * 64 + lane;
        a += tanhf(aw1S[wv][kk] + w2hS[kk]) * vL[kk];
      }
      a += __shfl_down(a, 32);
      a += __shfl_down(a, 16);
      a += __shfl_down(a, 8);
      a += __shfl_down(a, 4);
      a += __shfl_down(a, 2);
      a += __shfl_down(a, 1);
      if (lane == 0) logitL[wv] = a;
    }
    __syncthreads();
    if (tid < 64) {                          // wave 0: selection (R10 math)
      float lg = 0.0f, sgum = -1e30f;
      if (tid < L) {
        lg = 1.1f * tanhf(logitL[tid] * 0.2f);
        U2 sk = tf2x32(bk.x, bk.y, 0u, (uint32_t)step);
        U2 r2 = tf2x32(sk.x, sk.y, 0u, (uint32_t)tid);
        uint32_t bits = r2.x ^ r2.y;
        float u = __uint_as_float((bits >> 9) | 0x3f800000u) - 1.0f;
        u = fmaxf(TINYF, u + TINYF);         // jax uniform(tiny, 1)
        sgum = lg - logf(-logf(u));
      }
      int bi = 0;
      float best = __shfl(sgum, 0, 64);
      for (int j = 1; j < L; ++j) {
        float sj = __shfl(sgum, j, 64);
        if (sj > best) { best = sj; bi = j; }     // first-max = jnp.argmax
      }
      float mx = __shfl(lg, 0, 64);
      for (int j = 1; j < L; ++j) mx = fmaxf(mx, __shfl(lg, j, 64));
      float se = 0.0f;
      for (int j = 0; j < L; ++j) se += expf(__shfl(lg, j, 64) - mx);
      float lse = logf(se);
      float lgbi = __shfl(lg, bi, 64);
      float es = 0.0f;
      for (int j = 0; j < L; ++j) {
        float l = __shfl(lg, j, 64) - mx - lse;
        es += l * expf(l);
      }
      if (tid == 0) {
        lpAcc += -(lgbi - mx - lse);
        entAcc += -es;
        selL = bi;
        if (p == 0) out[b * 10 + step] = (float)bi;
      }
    }
    __syncthreads();
    step++;
    return selL;
  };

  // ---- chain ----
  cell(encih, 1, 0, -1);             // zero-state cell; all wgs get aw1[0]
  if (tid < 256) aw1S[1][tid] = aw1S[0][tid];
  __syncthreads();

  for (int L = 2; L <= 6; ++L) {
    { float hh = dotHH(); cell(encih + hh, 0, 0, -1); }          // cellA
    {
      float hh = dotHH();
      int s1 = resolve(L);
      float a = (s1 >= 2) ? dotIH(&anchL[s1 - 2][0]) : 0.0f;
      cell(a + hh, 0, 0, -1);                                    // cellB
    }
    {
      float hh = dotHH();
      int s2 = resolve(L);
      float a = (s2 >= 2) ? dotIH(&anchL[s2 - 2][0]) : 0.0f;
      if (L < 6) cell(a + hh, 1, L, L - 2);                      // cellC anchor
      else       cell(a + hh, 2, 0, -1);                         // last cell
    }
  }

  if (p == 0 && tid == 0) {
    fstore(&part[2 * b], lpAcc);
    fstore(&part[2 * b + 1], entAcc);
    __builtin_amdgcn_s_waitcnt(0);
    istore(&done[b], DONE_MAGIC);
    if (b == NBLK - 1) {
      float lp = 0.0f, en = 0.0f;
      for (int j = 0; j < NBLK; ++j) {
        while (iload(&done[j]) != DONE_MAGIC) __builtin_amdgcn_s_sleep(1);
        lp += fload(&part[2 * j]);
        en += fload(&part[2 * j + 1]);
      }
      out[60] = lp;
      out[61] = en;
    }
  }
}

// =================== fallback (proven R8-style; small ws) ==================
__global__ __launch_bounds__(1024) void ctrl_small(
    const float* __restrict__ enc_w,
    const float* __restrict__ wih,
    const float* __restrict__ whh,
    const float* __restrict__ b_ih,
    const float* __restrict__ b_hh,
    const float* __restrict__ w1,
    const float* __restrict__ w2,
    const float* __restrict__ vvec,
    unsigned char* __restrict__ ws,
    float* __restrict__ out) {

  const int b = blockIdx.x & 7;
  const int p = blockIdx.x >> 3;
  if (b >= NBLK) return;
  const int tid = threadIdx.x;

  int*   ready = (int*)(ws + S_READY);
  int*   done  = (int*)(ws + S_DONE);
  float* part  = (float*)(ws + S_PART);
  u64*   hp    = (u64*)(ws + S_HP);
  int*   acc   = (int*)(ws + S_ACC);

  const int rl = tid >> 3, s = tid & 7;
  const int g = rl >> 5, el = rl & 31;
  const int row = g * 256 + p * 32 + el;
  const int k0 = s * 32;
  const int rr = tid & 255, ks = tid >> 8;

  __shared__ __align__(16) float hL[256], encL[256], vL[256];
  __shared__ __align__(16) float anchL[4][256];
  __shared__ __align__(16) float partL[1024];
  __shared__ __align__(16) float w2hS[256], aw1S[6][256];
  __shared__ float rowSumL[128], biasS[128], h2S[32];
  __shared__ float logitL[8];
  __shared__ int   selL;

  if (tid < 256) { encL[tid] = enc_w[tid]; vL[tid] = vvec[tid]; }
  if (tid < 128) {
    int gg = tid >> 5, ee = tid & 31, r = gg * 256 + p * 32 + ee;
    biasS[tid] = b_ih[r] + b_hh[r];
  }

  float4 wihr[8], whhr[8];
  #pragma unroll
  for (int c = 0; c < 8; ++c) {
    int cc = (c + s) & 7;
    wihr[c] = *(const float4*)(wih + row * 256 + k0 + cc * 4);
    whhr[c] = *(const float4*)(whh + row * 256 + k0 + cc * 4);
  }
  float w1c[8], w2c[8];
  #pragma unroll
  for (int j = 0; j < 8; ++j) {
    w1c[j] = w1[rr * 256 + p * 32 + ks * 8 + j];
    w2c[j] = w2[rr * 256 + p * 32 + ks * 8 + j];
  }

  if (tid < 32) istore(&acc[1 * (NBLK * 256) + b * 256 + p * 32 + tid], 0);
  __syncthreads();
  if (tid == 0) istore(&ready[b * 8 + p], READY_MAGIC);
  if (tid < 8) {
    while (iload(&ready[b * 8 + tid]) != READY_MAGIC)
      __builtin_amdgcn_s_sleep(1);
  }
  __syncthreads();

  auto dotIH = [&](const float* x) {
    float a = 0.0f;
    #pragma unroll
    for (int c = 0; c < 8; ++c) {
      int cc = (c + s) & 7;
      float4 xv = *(const float4*)(x + k0 + cc * 4);
      float4 w = wihr[c];
      a += w.x * xv.x + w.y * xv.y + w.z * xv.z + w.w * xv.w;
    }
    return a;
  };
  auto dotHH = [&]() {
    float a = 0.0f;
    #pragma unroll
    for (int c = 0; c < 8; ++c) {
      int cc = (c + s) & 7;
      float4 xv = *(const float4*)(hL + k0 + cc * 4);
      float4 w = whhr[c];
      a += w.x * xv.x + w.y * xv.y + w.z * xv.z + w.w * xv.w;
    }
    return a;
  };

  const float encih = dotIH(encL);
  float cv = 0.0f;
  U2 bk = tf2x32(0u, 42u, 0u, (uint32_t)b);
  int k = 1, step = 0;
  float lpAcc = 0.0f, entAcc = 0.0f;

  auto cell = [&](float gacc, int mode, int aid, int cid) {
    partL[tid] = gacc;
    __syncthreads();
    if (tid < 128) {
      float ssum = 0.0f;
      #pragma unroll
      for (int j = 0; j < 8; ++j) ssum += partL[tid * 8 + j];
      rowSumL[tid] = ssum + biasS[tid];
    }
    __syncthreads();
    if (tid < 32) {
      float gi = rowSumL[tid],       gf = rowSumL[32 + tid];
      float gg2 = rowSumL[64 + tid], go = rowSumL[96 + tid];
      float c2 = sigf(gf) * cv + sigf(gi) * tanhf(gg2);
      float h2 = sigf(go) * tanhf(c2);
      cv = c2;
      h2S[tid] = h2;
      if (mode == 2 && b == NBLK - 1) {
        out[62 + p * 32 + tid] = cv;
        out[318 + p * 32 + tid] = h2;
      }
    }
    __syncthreads();
    if (mode == 2) return;
    {
      const float* wc = (mode == 1) ? w1c : w2c;
      float yp = 0.0f;
      #pragma unroll
      for (int j = 0; j < 8; ++j) yp += wc[j] * h2S[ks * 8 + j];
      atomicAdd(&acc[(k % 3) * (NBLK * 256) + b * 256 + rr],
                __float2int_rn(yp * FXS));
      if (tid < 32)
        istore(&acc[((k + 1) % 3) * (NBLK * 256) + b * 256 + p * 32 + tid], 0);
    }
    __syncthreads();
    if (tid < 32) {
      u64 pk = ((u64)(uint32_t)k << 32) | (u64)__float_as_uint(h2S[tid]);
      hstore(&hp[(k & 1) * (NBLK * 256) + b * 256 + p * 32 + tid], pk);
    }
    if (tid < 256) {
      u64 v;
      const u64* src = &hp[(k & 1) * (NBLK * 256) + b * 256 + tid];
      while ((int)(hload(src) >> 32) != k) __builtin_amdgcn_s_sleep(1);
      v = hload(src);
      float hv = __uint_as_float((uint32_t)v);
      hL[tid] = hv;
      if (mode == 1 && cid >= 0) anchL[cid][tid] = hv;
    }
    __syncthreads();
    if (tid < 256) {
      int iv = iload(&acc[(k % 3) * (NBLK * 256) + b * 256 + tid]);
      float f = (float)((double)iv * (1.0 / 67108864.0));
      if (mode == 1) aw1S[aid][tid] = f; else w2hS[tid] = f;
    }
    __syncthreads();
    ++k;
  };

  auto sample = [&](int L) -> int {
    int wv = tid >> 6, lane = tid & 63;
    if (wv < L) {
      float a = 0.0f;
      #pragma unroll
      for (int j = 0; j < 4; ++j) {
        int kk = lane * 4 + j;
        a += tanhf(aw1S[wv][kk] + w2hS[kk]) * vL[kk];
      }
      a += __shfl_down(a, 32);
      a += __shfl_down(a, 16);
      a += __shfl_down(a, 8);
      a += __shfl_down(a, 4);
      a += __shfl_down(a, 2);
      a += __shfl_down(a, 1);
      if (lane == 0) logitL[wv] = a;
    }
    __syncthreads();
    if (tid < 64) {
      float lg = 0.0f, sgum = -1e30f;
      if (tid < L) {
        lg = 1.1f * tanhf(logitL[tid] * 0.2f);
        U2 sk = tf2x32(bk.x, bk.y, 0u, (uint32_t)step);
        U2 r2 = tf2x32(sk.x, sk.y, 0u, (uint32_t)tid);
        uint32_t bits = r2.x ^ r2.y;
        float u = __uint_as_float((bits >> 9) | 0x3f800000u) - 1.0f;
        u = fmaxf(TINYF, u + TINYF);
        sgum = lg - logf(-logf(u));
      }
      int bi = 0;
      float best = __shfl(sgum, 0, 64);
      for (int j = 1; j < L; ++j) {
        float sj = __shfl(sgum, j, 64);
        if (sj > best) { best = sj; bi = j; }
      }
      float mx = __shfl(lg, 0, 64);
      for (int j = 1; j < L; ++j) mx = fmaxf(mx, __shfl(lg, j, 64));
      float se = 0.0f;
      for (int j = 0; j < L; ++j) se += expf(__shfl(lg, j, 64) - mx);
      float lse = logf(se);
      float lgbi = __shfl(lg, bi, 64);
      float es = 0.0f;
      for (int j = 0; j < L; ++j) {
        float l = __shfl(lg, j, 64) - mx - lse;
        es += l * expf(l);
      }
      if (tid == 0) {
        lpAcc += -(lgbi - mx - lse);
        entAcc += -es;
        selL = bi;
        if (p == 0) out[b * 10 + step] = (float)bi;
      }
    }
    __syncthreads();
    step++;
    return selL;
  };

  cell(encih, 1, 0, -1);
  if (tid < 256) aw1S[1][tid] = aw1S[0][tid];
  __syncthreads();
  for (int L = 2; L <= 6; ++L) {
    cell(encih + dotHH(), 0, 0, -1);
    int s1v = sample(L);
    {
      float a = (s1v >= 2) ? dotIH(&anchL[s1v - 2][0]) : 0.0f;
      cell(a + dotHH(), 0, 0, -1);
    }
    int s2v = sample(L);
    {
      float a = (s2v >= 2) ? dotIH(&anchL[s2v - 2][0]) : 0.0f;
      if (L < 6) cell(a + dotHH(), 1, L, L - 2);
      else       cell(a + dotHH(), 2, 0, -1);
    }
  }
  if (p == 0 && tid == 0) {
    fstore(&part[2 * b], lpAcc);
    fstore(&part[2 * b + 1], entAcc);
    __builtin_amdgcn_s_waitcnt(0);
    istore(&done[b], DONE_MAGIC);
    if (b == NBLK - 1) {
      float lp = 0.0f, en = 0.0f;
      for (int j = 0; j < NBLK; ++j) {
        while (iload(&done[j]) != DONE_MAGIC) __builtin_amdgcn_s_sleep(1);
        lp += fload(&part[2 * j]);
        en += fload(&part[2 * j + 1]);
      }
      out[60] = lp;
      out[61] = en;
    }
  }
}

extern "C" void kernel_launch(void* const* d_in, const int* in_sizes, int n_in,
                              void* d_out, int out_size, void* d_ws, size_t ws_size,
                              hipStream_t stream) {
  const float* enc = (const float*)d_in[0];
  const float* wih = (const float*)d_in[1];
  const float* whh = (const float*)d_in[2];
  const float* bih = (const float*)d_in[3];
  const float* bhh = (const float*)d_in[4];
  const float* w1  = (const float*)d_in[5];
  const float* w2  = (const float*)d_in[6];
  const float* v   = (const float*)d_in[7];
  unsigned char* ws = (unsigned char*)d_ws;
  float* out = (float*)d_out;

  if (ws_size >= W_NEED) {
    ctrl_v13<<<dim3(64), dim3(THR), 0, stream>>>(
        enc, wih, whh, bih, bhh, w1, w2, v, ws, out);
  } else {
    ctrl_small<<<dim3(64), dim3(1024), 0, stream>>>(
        enc, wih, whh, bih, bhh, w1, w2, v, ws, out);
  }
}